// Round 5
// baseline (111.863 us; speedup 1.0000x reference)
//
#include <hip/hip_runtime.h>
#include <hip/hip_bf16.h>

// GradientLayer: 4->128->128->128->5 tanh MLP; per-sample Jacobian (5x4) and
// Hessians of outputs 0 and 4, combined into 17 outputs.
// Round 5 (from validated round 4):
//  - Coalesced block-wide output writer: per-wave comb2 staged in LDS (as in
//    round 4), then one __syncthreads and 152 threads write region-major,
//    consecutive threads -> consecutive addresses. Kills the 41 MB write
//    amplification (round 4 scattered 38 partial-line stores per wave).
//  - Core MFMA pipeline unchanged from the validated round-4 kernel.

namespace {

constexpr int HID = 128;

using bf16x8 = __attribute__((ext_vector_type(8))) short;
using f32x4  = __attribute__((ext_vector_type(4))) float;
typedef unsigned       __attribute__((may_alias)) u32a;
typedef unsigned short __attribute__((may_alias)) u16a;

#define LDS_FENCE() asm volatile("" ::: "memory")

struct OSpec {
    int base, mul, off;
    int a0, a1, a2, m;
    int b0, b1, b2, m2;
    float s1, s2;
};

// comb2[] indices: value (v,k) at v*5+k, v in 0..14, k in 0..4.
// o_k = comb2[k]; J[k][d] = comb2[5+5d+k];
// Hn[p] = comb2[25+5p]; HFi[p] = comb2[29+5p]; comb2[80]=0, comb2[81]=1.
__constant__ OSpec g_ospec[38] = {
    {0,1,0,   0,80,80,81, 80,80,80,81, 1.f,0.f},   // n
    {1,1,0,   5,80,80,81, 80,80,80,81, 1.f,0.f},   // n_t
    {2,3,0,  10,80,80,81, 80,80,80,81, 1.f,0.f},   // n_grd
    {2,3,1,  15,80,80,81, 80,80,80,81, 1.f,0.f},
    {2,3,2,  20,80,80,81, 80,80,80,81, 1.f,0.f},
    {5,3,0,   1,80,80, 0, 80,80,80,81, 1.f,0.f},   // j = n*v
    {5,3,1,   2,80,80, 0, 80,80,80,81, 1.f,0.f},
    {5,3,2,   3,80,80, 0, 80,80,80,81, 1.f,0.f},
    {8,3,0,  10,15,20, 1, 11,16,21, 0, 1.f,1.f},   // j_div
    {8,3,1,  10,15,20, 2, 12,17,22, 0, 1.f,1.f},
    {8,3,2,  10,15,20, 3, 13,18,23, 0, 1.f,1.f},
    {11,1,0,  4,80,80,81, 80,80,80,81, 1.f,0.f},   // Fi
    {12,3,0, 14,80,80,81, 80,80,80,81, 1.f,0.f},   // Fi_grd
    {12,3,1, 19,80,80,81, 80,80,80,81, 1.f,0.f},
    {12,3,2, 24,80,80,81, 80,80,80,81, 1.f,0.f},
    {15,4,0, 34,39,44,81, 80,80,80,81, 1.f,0.f},   // Fi_lap (HFi p=1,2,3)
    {15,4,1, 49,54,59,81, 80,80,80,81, 1.f,0.f},   //        (p=4,5,6)
    {15,4,2, 54,64,69,81, 80,80,80,81, 1.f,0.f},   //        (p=5,7,8)
    {15,4,3, 59,69,74,81, 80,80,80,81, 1.f,0.f},   //        (p=6,8,9)
    {19,3,0,  1,80,80,81, 80,80,80,81, 1.f,0.f},   // v
    {19,3,1,  2,80,80,81, 80,80,80,81, 1.f,0.f},
    {19,3,2,  3,80,80,81, 80,80,80,81, 1.f,0.f},
    {22,1,0,  5,80,80,81, 80,80,80,81, 1.f,0.f},   // v_t
    {23,3,0,  1,80,80,10, 80,80,80,81, 1.f,0.f},   // v_adv
    {23,3,1,  2,80,80,15, 80,80,80,81, 1.f,0.f},
    {23,3,2,  3,80,80,20, 80,80,80,81, 1.f,0.f},
    {26,1,0, 30,50,65,81, 80,80,80,81, 1.f,0.f},   // v_lap (Hn p=1,5,8)
    {27,3,0, 45,50,55,81, 80,80,80,81, 1.f,0.f},   // v_div_grd (p=4,5,6)
    {27,3,1, 50,60,65,81, 80,80,80,81, 1.f,0.f},   //           (p=5,7,8)
    {27,3,2, 55,65,70,81, 80,80,80,81, 1.f,0.f},   //           (p=6,8,9)
    {30,1,0,  0,80,80,81, 80,80,80,81, 2.f,0.f},   // ro = 2n
    {31,1,0,  5,80,80,81, 80,80,80,81, 2.f,0.f},   // ro_t
    {32,3,0, 10,80,80,81, 80,80,80,81, 2.f,0.f},   // ro_grd
    {32,3,1, 15,80,80,81, 80,80,80,81, 2.f,0.f},
    {32,3,2, 20,80,80,81, 80,80,80,81, 2.f,0.f},
    {35,3,0, 10,15,20, 1, 11,16,21, 0, 2.f,2.f},   // rov_div
    {35,3,1, 10,15,20, 2, 12,17,22, 0, 2.f,2.f},
    {35,3,2, 10,15,20, 3, 13,18,23, 0, 2.f,2.f},
};

// Block-wide coalesced writer map: entry = ospec_idx | (sample_local << 6).
// Region-major, within region j = s*mul + off ascending -> consecutive
// addresses out[base*nb + (b0+s)*mul + off].
__constant__ unsigned char g_t2[152] = {
    // r0: n (oi 0, m1)
    0, 64, 128, 192,
    // r1: n_t (oi 1, m1)
    1, 65, 129, 193,
    // r2: n_grd (oi 2-4, m3)
    2,3,4, 66,67,68, 130,131,132, 194,195,196,
    // r3: j (oi 5-7, m3)
    5,6,7, 69,70,71, 133,134,135, 197,198,199,
    // r4: j_div (oi 8-10, m3)
    8,9,10, 72,73,74, 136,137,138, 200,201,202,
    // r5: Fi (oi 11, m1)
    11, 75, 139, 203,
    // r6: Fi_grd (oi 12-14, m3)
    12,13,14, 76,77,78, 140,141,142, 204,205,206,
    // r7: Fi_lap (oi 15-18, m4)
    15,16,17,18, 79,80,81,82, 143,144,145,146, 207,208,209,210,
    // r8: v (oi 19-21, m3)
    19,20,21, 83,84,85, 147,148,149, 211,212,213,
    // r9: v_t (oi 22, m1)
    22, 86, 150, 214,
    // r10: v_adv (oi 23-25, m3)
    23,24,25, 87,88,89, 151,152,153, 215,216,217,
    // r11: v_lap (oi 26, m1)
    26, 90, 154, 218,
    // r12: v_div_grd (oi 27-29, m3)
    27,28,29, 91,92,93, 155,156,157, 219,220,221,
    // r13: ro (oi 30, m1)
    30, 94, 158, 222,
    // r14: ro_t (oi 31, m1)
    31, 95, 159, 223,
    // r15: ro_grd (oi 32-34, m3)
    32,33,34, 96,97,98, 160,161,162, 224,225,226,
    // r16: rov_div (oi 35-37, m3)
    35,36,37, 99,100,101, 163,164,165, 227,228,229,
};

__device__ __forceinline__ unsigned short f2bf(float f) {
    union { float f; unsigned u; } v; v.f = f;
    unsigned r = v.u + 0x7FFFu + ((v.u >> 16) & 1u);   // RNE
    return (unsigned short)(r >> 16);
}
__device__ __forceinline__ unsigned pk_bf16(float lo, float hi) {
    __hip_bfloat162 h2 = __float22bfloat162_rn(make_float2(lo, hi));
    unsigned r; __builtin_memcpy(&r, &h2, 4); return r;   // lo in bits 0-15
}
__device__ __forceinline__ float tanh_fast(float z) {
    float e = __builtin_amdgcn_exp2f(z * 2.8853900817779268f);
    return 1.0f - 2.0f * __builtin_amdgcn_rcpf(e + 1.0f);
}
// swizzled byte offset inside the per-wave [16][128] bf16 A-buffer
__device__ __forceinline__ int swz(int row, int byte_in_row) {
    return (row * 256 + byte_in_row) ^ ((row & 7) << 4);
}

// ---- pack W1/W2 (+ W3 padded to 16 cols) into B-fragment bf16 in d_ws ------
__global__ void pack_w_kernel(const float* __restrict__ W1,
                              const float* __restrict__ W2,
                              const float* __restrict__ W3,
                              unsigned short* __restrict__ wsB) {
    int t = blockIdx.x * 256 + threadIdx.x;        // 0..34815
    if (t < 32768) {
        int reg  = t & 7;
        int lane = (t >> 3) & 63;
        int nt   = (t >> 9) & 7;
        int kt   = (t >> 12) & 3;
        int layer = (t >> 14) & 1;
        int k = kt * 32 + (lane >> 4) * 8 + reg;
        int n = nt * 16 + (lane & 15);
        const float* W = layer ? W2 : W1;
        wsB[t] = f2bf(W[k * HID + n]);
    } else if (t < 34816) {
        int tt = t - 32768;
        int reg  = tt & 7;
        int lane = (tt >> 3) & 63;
        int kt   = (tt >> 9) & 3;
        int k = kt * 32 + (lane >> 4) * 8 + reg;
        int n = lane & 15;
        wsB[t] = (n < 5) ? f2bf(W3[k * 5 + n]) : (unsigned short)0;
    }
}

__global__ __launch_bounds__(256, 8) void mlp_pde_kernel(
    const float* __restrict__ x,
    const float* __restrict__ W0, const float* __restrict__ b0,
    const float* __restrict__ b1, const float* __restrict__ b2,
    const float* __restrict__ b3,
    const unsigned short* __restrict__ wsB,
    float* __restrict__ out, int nb)
{
    constexpr int PD[10] = {0,0,0,0,1,1,1,2,2,3};
    constexpr int PE[10] = {0,1,2,3,1,2,3,2,3,3};

    __shared__ float lds[4][1120];                 // 4480 B per wave, 17920 B/block
    const int wave = threadIdx.x >> 6;
    const int lane = threadIdx.x & 63;
    char* abuf = (char*)lds[wave];                 // first 4096 B: [16][128] bf16 (swizzled)
    const int b0s = blockIdx.x * 4;
    int b = b0s + wave;
    if (b >= nb) b = nb - 1;

    // ---------------- layer 0 (4 -> 128), fp32, lane owns cols 2l,2l+1 ------
    {
        const int j0 = lane * 2;
        const float4 xv = *reinterpret_cast<const float4*>(x + 4 * b);
        float w0d[4][2];
        #pragma unroll
        for (int d = 0; d < 4; ++d) {
            float2 w = *reinterpret_cast<const float2*>(W0 + d * HID + j0);
            w0d[d][0] = w.x; w0d[d][1] = w.y;
        }
        const float2 bb0 = *reinterpret_cast<const float2*>(b0 + j0);
        float val[15][2];
        #pragma unroll
        for (int jj = 0; jj < 2; ++jj) {
            float z = ((jj == 0) ? bb0.x : bb0.y)
                    + xv.x * w0d[0][jj] + xv.y * w0d[1][jj]
                    + xv.z * w0d[2][jj] + xv.w * w0d[3][jj];
            float h = tanh_fast(z);
            float s = 1.f - h * h;
            val[0][jj] = h;
            #pragma unroll
            for (int d = 0; d < 4; ++d) val[1 + d][jj] = s * w0d[d][jj];
            #pragma unroll
            for (int p = 0; p < 10; ++p)
                val[5 + p][jj] = -2.f * h * s * w0d[PD[p]][jj] * w0d[PE[p]][jj];
        }
        #pragma unroll
        for (int v = 0; v < 15; ++v)
            *reinterpret_cast<u32a*>(abuf + swz(v, j0 * 2)) = pk_bf16(val[v][0], val[v][1]);
        *reinterpret_cast<u32a*>(abuf + swz(15, j0 * 2)) = 0u;  // pad row
    }
    LDS_FENCE();   // layer-0 stores -> afrag reads

    // ---------------- layers 1,2 via MFMA -----------------------------------
    const int jloc = lane & 15;                    // column within 16-wide tile
    const int rgrp = lane >> 4;                    // row group: rows 4r..4r+3
    #pragma unroll 1
    for (int layer = 0; layer < 2; ++layer) {
        // A fragments: lane holds A[m = lane&15][k = kt*32 + (lane>>4)*8 + 0..7]
        bf16x8 afrag[4];
        #pragma unroll
        for (int kt = 0; kt < 4; ++kt)
            afrag[kt] = *reinterpret_cast<const bf16x8*>(
                abuf + (swz(jloc, kt * 64 + rgrp * 16)));
        LDS_FENCE();   // afrag reads -> recombination stores (WAR)
        const float* bias = layer ? b2 : b1;
        float bv[8];
        #pragma unroll
        for (int nt = 0; nt < 8; ++nt) bv[nt] = bias[nt * 16 + jloc];

        #pragma unroll 1
        for (int nt = 0; nt < 8; ++nt) {
            f32x4 acc = {0.f, 0.f, 0.f, 0.f};
            #pragma unroll
            for (int kt = 0; kt < 4; ++kt) {
                bf16x8 bfrag = *reinterpret_cast<const bf16x8*>(
                    wsB + ((size_t)((layer * 4 + kt) * 8 + nt) * 512 + lane * 8));
                acc = __builtin_amdgcn_mfma_f32_16x16x32_bf16(afrag[kt], bfrag, acc, 0, 0, 0);
            }
            // broadcast primal + first-order tangents within the column group
            float z0 = __shfl(acc[0], jloc, 64);         // row 0 (primal z)
            float u0 = __shfl(acc[1], jloc, 64);         // row 1 (dz_0)
            float u1 = __shfl(acc[2], jloc, 64);         // row 2 (dz_1)
            float u2 = __shfl(acc[3], jloc, 64);         // row 3 (dz_2)
            float u3 = __shfl(acc[0], jloc + 16, 64);    // row 4 (dz_3)
            float h = tanh_fast(z0 + bv[nt]);
            float s = 1.f - h * h;
            float c = -2.f * h * s;
            float nv[4];
            if (rgrp == 0) {
                nv[0] = h;           nv[1] = s * u0;
                nv[2] = s * u1;      nv[3] = s * u2;
            } else if (rgrp == 1) {
                nv[0] = s * u3;
                nv[1] = fmaf(c * u0, u0, s * acc[1]);    // row 5  (0,0)
                nv[2] = fmaf(c * u0, u1, s * acc[2]);    // row 6  (0,1)
                nv[3] = fmaf(c * u0, u2, s * acc[3]);    // row 7  (0,2)
            } else if (rgrp == 2) {
                nv[0] = fmaf(c * u0, u3, s * acc[0]);    // row 8  (0,3)
                nv[1] = fmaf(c * u1, u1, s * acc[1]);    // row 9  (1,1)
                nv[2] = fmaf(c * u1, u2, s * acc[2]);    // row 10 (1,2)
                nv[3] = fmaf(c * u1, u3, s * acc[3]);    // row 11 (1,3)
            } else {
                nv[0] = fmaf(c * u2, u2, s * acc[0]);    // row 12 (2,2)
                nv[1] = fmaf(c * u2, u3, s * acc[1]);    // row 13 (2,3)
                nv[2] = fmaf(c * u3, u3, s * acc[2]);    // row 14 (3,3)
                nv[3] = 0.f;                             // pad row 15
            }
            unsigned pk01 = pk_bf16(nv[0], nv[1]);
            unsigned pk23 = pk_bf16(nv[2], nv[3]);
            const int bcol = (nt * 16 + jloc) * 2;
            *reinterpret_cast<u16a*>(abuf + swz(rgrp * 4 + 0, bcol)) = (unsigned short)pk01;
            *reinterpret_cast<u16a*>(abuf + swz(rgrp * 4 + 1, bcol)) = (unsigned short)(pk01 >> 16);
            *reinterpret_cast<u16a*>(abuf + swz(rgrp * 4 + 2, bcol)) = (unsigned short)pk23;
            *reinterpret_cast<u16a*>(abuf + swz(rgrp * 4 + 3, bcol)) = (unsigned short)(pk23 >> 16);
        }
        LDS_FENCE();   // recombination stores -> next-layer / epilogue reads
    }

    // ---------------- epilogue: T(16x128) @ W3pad(128x16) via MFMA ----------
    bf16x8 tfrag[4];
    #pragma unroll
    for (int kt = 0; kt < 4; ++kt)
        tfrag[kt] = *reinterpret_cast<const bf16x8*>(
            abuf + (swz(jloc, kt * 64 + rgrp * 16)));
    LDS_FENCE();

    f32x4 facc = {0.f, 0.f, 0.f, 0.f};
    #pragma unroll
    for (int kt = 0; kt < 4; ++kt) {
        bf16x8 w3f = *reinterpret_cast<const bf16x8*>(
            wsB + 32768 + (size_t)(kt * 64 + lane) * 8);
        facc = __builtin_amdgcn_mfma_f32_16x16x32_bf16(tfrag[kt], w3f, facc, 0, 0, 0);
    }

    float* comb2 = lds[wave] + 1024;               // 82 slots
    if (jloc < 5) {
        #pragma unroll
        for (int q = 0; q < 4; ++q) {
            int row = rgrp * 4 + q;                // = vector index v
            float t = facc[q];
            if (row == 0) t += b3[jloc];
            comb2[row * 5 + jloc] = t;             // rows 0..15 -> slots 0..79
        }
    }
    if (lane == 63) { comb2[80] = 0.f; comb2[81] = 1.f; }
    __syncthreads();   // all waves' comb2 visible block-wide

    // ---------------- block-wide coalesced writer ---------------------------
    const int t = threadIdx.x;
    if (t < 152) {
        unsigned e = g_t2[t];
        int oi = e & 63;
        int s  = e >> 6;
        OSpec sp = g_ospec[oi];
        const float* c2 = lds[s] + 1024;
        float t1 = (c2[sp.a0] + c2[sp.a1] + c2[sp.a2]) * c2[sp.m] * sp.s1;
        float t2 = (c2[sp.b0] + c2[sp.b1] + c2[sp.b2]) * c2[sp.m2] * sp.s2;
        int bs = b0s + s;
        if (bs >= nb) bs = nb - 1;                 // benign duplicate on tail
        out[sp.base * nb + bs * sp.mul + sp.off] = t1 + t2;
    }
}

} // namespace

extern "C" void kernel_launch(void* const* d_in, const int* in_sizes, int n_in,
                              void* d_out, int out_size, void* d_ws, size_t ws_size,
                              hipStream_t stream) {
    const float* x  = (const float*)d_in[0];
    const float* W0 = (const float*)d_in[1];
    const float* b0 = (const float*)d_in[2];
    const float* W1 = (const float*)d_in[3];
    const float* b1 = (const float*)d_in[4];
    const float* W2 = (const float*)d_in[5];
    const float* b2 = (const float*)d_in[6];
    const float* W3 = (const float*)d_in[7];
    const float* b3 = (const float*)d_in[8];
    float* out = (float*)d_out;
    unsigned short* wsB = (unsigned short*)d_ws;   // ~68 KB used

    const int nb = in_sizes[0] / 4;                // 32768
    pack_w_kernel<<<136, 256, 0, stream>>>(W1, W2, W3, wsB);
    const int blocks = (nb + 3) / 4;
    mlp_pde_kernel<<<blocks, 256, 0, stream>>>(x, W0, b0, b1, b2, b3, wsB, out, nb);
}